// Round 15
// baseline (74.087 us; speedup 1.0000x reference)
//
#include <hip/hip_runtime.h>

static constexpr int BATCH = 128;
static constexpr int LEN   = 131072;
static constexpr int T     = 4096;   // LEN / 32
static constexpr int DIM   = 32;
static constexpr int NP    = 16;

static constexpr int NCHUNK = 64;         // speculative chunks over T
static constexpr int SPC    = T / NCHUNK; // 64 steps per chunk
static constexpr int WARM   = 128;        // warm-up steps (0.9375^128 ~ 2.6e-4)

static constexpr int TT = 128;            // windows per scores-block

#define L2E   1.44269504088896340736f
#define L2E16 (1.44269504088896340736f / 16.0f)

typedef __attribute__((ext_vector_type(8))) short  short8;   // 8 bf16
typedef __attribute__((ext_vector_type(4))) float  f32x4;

__device__ __forceinline__ float fexp2(float x) {
#if __has_builtin(__builtin_amdgcn_exp2f)
  return __builtin_amdgcn_exp2f(x);
#else
  return exp2f(x);
#endif
}

__device__ __forceinline__ float frcp(float x) {
#if __has_builtin(__builtin_amdgcn_rcpf)
  return __builtin_amdgcn_rcpf(x);
#else
  return 1.0f / x;
#endif
}

template <int CTRL>
__device__ __forceinline__ float dppf(float v) {
  return __int_as_float(
      __builtin_amdgcn_update_dpp(0, __float_as_int(v), CTRL, 0xf, 0xf, true));
}

// Sum across each 16-lane group: butterfly over xor {1,2,7,15} via DPP.
__device__ __forceinline__ float sum16(float v) {
  v += dppf<0xB1>(v);
  v += dppf<0x4E>(v);
  v += dppf<0x141>(v);
  v += dppf<0x140>(v);
  return v;
}

// f32 -> bf16 round-to-nearest-even.
__device__ __forceinline__ short bf16c(float f) {
  unsigned u = __float_as_uint(f);
  unsigned r = u + 0x7fffu + ((u >> 16) & 1u);
  return (short)(r >> 16);
}

// One-shot prep: build bf16 MFMA fragments for conv_w / keys / bias in the
// exact per-lane layout scores_kernel consumes.
// Layout (shorts): [fs=fn*2+fk][lane][8] (4x1KB), kfrag [lane][8] (1KB),
// bias float2[lane] (512B). Total 5.6KB -> L1/L2-resident.
__global__ void __launch_bounds__(64) prep_kernel(
    const float* __restrict__ conv_w, const float* __restrict__ conv_b,
    const float* __restrict__ keys, short* __restrict__ frags) {
  int l = threadIdx.x;
  int ln15 = l & 15, kg = l >> 4;
#pragma unroll
  for (int fn = 0; fn < 2; ++fn)
#pragma unroll
    for (int fk = 0; fk < 2; ++fk) {
      const float* wp = conv_w + (fn * 16 + ln15) * 64 + fk * 32 + kg * 8;
      short* dst = frags + ((fn * 2 + fk) * 64 + l) * 8;
#pragma unroll
      for (int j = 0; j < 8; ++j) dst[j] = bf16c(wp[j]);
    }
  short* kd = frags + (256 + l) * 8;
#pragma unroll
  for (int j = 0; j < 8; ++j) kd[j] = bf16c(keys[(kg * 8 + j) * NP + ln15]);
  float* bp = (float*)(frags + 2560);
  bp[2 * l]     = conv_b[ln15];
  bp[2 * l + 1] = conv_b[16 + ln15];
}

// Stage 1 (MFMA, barrier-free): block = 256 thr (4 waves), one b, TT=128
// windows; each WAVE owns 32 windows and stages its OWN 2.1KB x-slice into a
// private LDS region -> no __syncthreads at all (same-wave DS ops are
// in-order). conv as GEMM via 16x16x32 bf16 MFMA (K=64 in 2 steps, N=32 in
// 2 tiles), relu+bias in D-layout, transpose through padded LDS (row stride
// 80B: conflict-free), MFMA vs keys. Fragment layouts (m89-verified):
// A row=l&15,k=(l>>4)*8+j; B col=l&15, same k; C/D col=l&15, row=(l>>4)*4+reg.
__global__ void __launch_bounds__(256) scores_kernel(
    const float* __restrict__ x, const short* __restrict__ frags,
    _Float16* __restrict__ scoresh) {
  // per wave: xw[1088] (windows) + rl[16 rows x 40 shorts padded] = 1728 shorts
  __shared__ short lds[4][1728];

  int tid = threadIdx.x;
  int lane = tid & 63;
  int mt   = tid >> 6;     // wave id
  int blk = blockIdx.x;
  int b  = blk >> 5;
  int bt = blk & 31;
  int t0 = bt * TT;
  int T0w = t0 + mt * 32;              // this wave's first window
  const float* xb = x + (size_t)b * LEN;
  short* xw = lds[mt];                 // xw[i] = bf16(x[32*T0w - 63 + i]), i<1056
  short* rl = lds[mt] + 1088;          // relu(conv) [t][d], row stride 40

  // ---- per-wave staging: lane covers xw[16*lane-1 .. 16*lane+15].
  int gbase = 32 * T0w - 64 + 16 * lane;
  float f[17];
#pragma unroll
  for (int s = 0; s < 4; ++s) {
    int gi = gbase + 4 * s;
    float4 v = make_float4(0.f, 0.f, 0.f, 0.f);
    if (gi >= 0) v = *(const float4*)(xb + gi);   // 16B-aligned
    f[4 * s]     = v.x; f[4 * s + 1] = v.y;
    f[4 * s + 2] = v.z; f[4 * s + 3] = v.w;
  }
  f[16] = (gbase + 16 >= 0) ? xb[gbase + 16] : 0.f;

  short8 w0, w1;
#pragma unroll
  for (int j = 0; j < 8; ++j) { w0[j] = bf16c(f[j + 1]); w1[j] = bf16c(f[j + 9]); }
  *(short8*)(&xw[16 * lane])     = w0;
  *(short8*)(&xw[16 * lane + 8]) = w1;
  if (lane > 0) xw[16 * lane - 1] = bf16c(f[0]);
  if (lane < 32)                        // tail: xw[1024..1055] (global +961..+992)
    xw[1024 + lane] = bf16c(xb[32 * T0w + 961 + lane]);

  int ln15 = lane & 15;
  int kg   = lane >> 4;    // 0..3

  // Prebuilt fragments: 5x16B + 8B, coalesced, L2-hot.
  const short8* wf = (const short8*)frags;
  short8 bw00 = wf[0 * 64 + lane];
  short8 bw01 = wf[1 * 64 + lane];
  short8 bw10 = wf[2 * 64 + lane];
  short8 bw11 = wf[3 * 64 + lane];
  short8 bk   = wf[4 * 64 + lane];
  const float2* bp = (const float2*)(frags + 2560);
  float2 bias = bp[lane];

  _Float16* dstb = scoresh + (b & 3) * 16 + ln15;

#pragma unroll
  for (int st = 0; st < 2; ++st) {
    int tl = st * 16 + ln15;                     // window row within wave
    const short* ap = &xw[32 * tl];              // 16B-aligned (64B row stride)
    short8 a0 = *(const short8*)(ap + kg * 8);
    short8 a1 = *(const short8*)(ap + 32 + kg * 8);

    f32x4 acc0 = {0.f, 0.f, 0.f, 0.f};
    f32x4 acc1 = {0.f, 0.f, 0.f, 0.f};
    acc0 = __builtin_amdgcn_mfma_f32_16x16x32_bf16(a0, bw00, acc0, 0, 0, 0);
    acc0 = __builtin_amdgcn_mfma_f32_16x16x32_bf16(a1, bw01, acc0, 0, 0, 0);
    acc1 = __builtin_amdgcn_mfma_f32_16x16x32_bf16(a0, bw10, acc1, 0, 0, 0);
    acc1 = __builtin_amdgcn_mfma_f32_16x16x32_bf16(a1, bw11, acc1, 0, 0, 0);

    // relu(conv+bias) -> bf16 -> padded LDS [t][d] (transpose).
    // Row stride 40 shorts = 80B: kg*320B % 128B = {0,64} -> 2-way (free).
#pragma unroll
    for (int r = 0; r < 4; ++r) {
      int trow = kg * 4 + r;                     // D row = (l>>4)*4 + r
      rl[trow * 40 + ln15]      = bf16c(fmaxf(acc0[r] + bias.x, 0.f));
      rl[trow * 40 + 16 + ln15] = bf16c(fmaxf(acc1[r] + bias.y, 0.f));
    }
    // Same-wave DS ops are in-order: no barrier needed (reads see writes,
    // next st's writes can't pass this read - WAR safe).
    short8 a2 = *(const short8*)(&rl[ln15 * 40 + kg * 8]);  // 80B rows: aligned
    f32x4 acc2 = {0.f, 0.f, 0.f, 0.f};
    acc2 = __builtin_amdgcn_mfma_f32_16x16x32_bf16(a2, bk, acc2, 0, 0, 0);

    // D2: p = ln15, t = T0w + st*16 + kg*4 + r. clip*log2e -> f16.
#pragma unroll
    for (int r = 0; r < 4; ++r) {
      float s = fminf(fmaxf(acc2[r], 0.f), 6.f) * L2E;
      int t = T0w + st * 16 + kg * 4 + r;
      dstb[((size_t)(b >> 2) * T + t) * 64] = (_Float16)s;
    }
  }
}

// Stage 2+3 FUSED v4: 256-thread blocks (4 waves). Wave 0 runs the scan
// (its 64 lanes = 4 batches x 16 patterns, 16-deep q-prefetch); waves 1-3
// each own one batch of the out-phase and issue their 16 stream loads AT
// ENTRY -- the loads complete under wave 0's ~5us scan. After the barrier
// all 4 waves compute+store one batch each. R12/R13/R14 all pinned at
// ~56us with 8 waves/CU; streaming BW on this chip tracks resident waves
// (standalone out: VGPR=8, 32 waves/CU, 5.1TB/s), so 4 waves/block +
// VGPR<=128 gives 16-20 waves/CU streaming and overlaps noise reads with
// the scan for the first time.
__global__ void __launch_bounds__(256, 4) scanout_kernel(
    const _Float16* __restrict__ scoresh, const float* __restrict__ avg0,
    const float* __restrict__ shapes, const float* __restrict__ x,
    const float* __restrict__ noise, float* __restrict__ out) {
  __shared__ float2 oslds[4][64];    // [local batch][t within chunk]

  int tid  = threadIdx.x;
  int lane = tid & 63;
  int wid  = tid >> 6;       // wave id = local batch for the out-phase
  int g = blockIdx.x & 31;   // batch-group (4 batches)
  int c = blockIdx.x >> 5;   // chunk

  size_t base = (size_t)(g * 4) * LEN + (size_t)c * 2048;
  const float* xp = x     + base + (size_t)wid * LEN + lane * 4;
  const float* np = noise + base + (size_t)wid * LEN + lane * 4;

  float4 xv[8], nv[8];
  if (wid != 0) {
    // Issue early: completes during wave 0's scan. Static indices -> regs.
#pragma unroll
    for (int k = 0; k < 8; ++k) {
      xv[k] = *(const float4*)(xp + k * 256);
      nv[k] = *(const float4*)(np + k * 256);
    }
  } else {
    // ---- wave 0: speculative scan (identical to R12's) ----
    int gid = g * 64 + lane;   // = b*16 + p
    int p = lane & 15;
    int bl = lane >> 4;        // local batch 0..3
    float A = avg0[gid] * L2E;
    float sh0 = shapes[2 * p];
    float sh1 = shapes[2 * p + 1];
    int w = min(WARM, c * SPC);      // c=0 exact; w in {0,64,128} (%16==0)
    int tbeg = c * SPC - w;
    const _Float16* sp = scoresh + ((size_t)g * T + tbeg) * 64 + lane;

    float q0 = (float)sp[0 * 64],  q1 = (float)sp[1 * 64];
    float q2 = (float)sp[2 * 64],  q3 = (float)sp[3 * 64];
    float q4 = (float)sp[4 * 64],  q5 = (float)sp[5 * 64];
    float q6 = (float)sp[6 * 64],  q7 = (float)sp[7 * 64];
    float q8 = (float)sp[8 * 64],  q9 = (float)sp[9 * 64];
    float qa = (float)sp[10 * 64], qb = (float)sp[11 * 64];
    float qc = (float)sp[12 * 64], qd = (float)sp[13 * 64];
    float qe = (float)sp[14 * 64], qf = (float)sp[15 * 64];
    sp += 16 * 64;

#define WSTEP(Q)                                   \
  do {                                             \
    float e = fexp2(Q - A);                        \
    float r = sum16(e);                            \
    A = fmaf(e * L2E, frcp(r), A - L2E16);         \
    Q = (float)sp[0];                              \
    sp += 64;                                      \
  } while (0)

    for (int i = 0; i < w; i += 16) {
      WSTEP(q0); WSTEP(q1); WSTEP(q2); WSTEP(q3);
      WSTEP(q4); WSTEP(q5); WSTEP(q6); WSTEP(q7);
      WSTEP(q8); WSTEP(q9); WSTEP(qa); WSTEP(qb);
      WSTEP(qc); WSTEP(qd); WSTEP(qe); WSTEP(qf);
    }

#define CSTEP(Q, idx)                              \
  do {                                             \
    float e = fexp2(Q - A);                        \
    float r  = sum16(e);                           \
    float u0 = sum16(e * sh0);                     \
    float u1 = sum16(e * sh1);                     \
    float rc = frcp(r);                            \
    A = fmaf(e * L2E, rc, A - L2E16);              \
    if (p == 0) oslds[bl][idx] = make_float2(u0 * rc, u1 * rc); \
    Q = (float)sp[0];                              \
    sp += 64;                                      \
  } while (0)

    for (int i = 0; i < SPC; i += 16) {            // overrun covered by ws pad
      CSTEP(q0, i + 0);  CSTEP(q1, i + 1);  CSTEP(q2, i + 2);  CSTEP(q3, i + 3);
      CSTEP(q4, i + 4);  CSTEP(q5, i + 5);  CSTEP(q6, i + 6);  CSTEP(q7, i + 7);
      CSTEP(q8, i + 8);  CSTEP(q9, i + 9);  CSTEP(qa, i + 10); CSTEP(qb, i + 11);
      CSTEP(qc, i + 12); CSTEP(qd, i + 13); CSTEP(qe, i + 14); CSTEP(qf, i + 15);
    }
#undef WSTEP
#undef CSTEP

    // wave 0's own stream loads (latency covered by waves 1-3 on the SIMD).
#pragma unroll
    for (int k = 0; k < 8; ++k) {
      xv[k] = *(const float4*)(xp + k * 256);
      nv[k] = *(const float4*)(np + k * 256);
    }
  }

  __syncthreads();   // oslds (wave 0) visible to all waves

  // ---- out phase: wave wid streams batch 4g+wid, elems [2048c, +2048).
  float* op = out + base + (size_t)wid * LEN + lane * 4;
#pragma unroll
  for (int k = 0; k < 8; ++k) {
    float2 os = oslds[wid][k * 8 + (lane >> 3)];   // t = c*64 + k*8 + (lane>>3)
    float4 o;
    o.x = fmaxf(fmaf(nv[k].x, os.y, os.x) - xv[k].x, 0.f);
    o.y = fmaxf(fmaf(nv[k].y, os.y, os.x) - xv[k].y, 0.f);
    o.z = fmaxf(fmaf(nv[k].z, os.y, os.x) - xv[k].z, 0.f);
    o.w = fmaxf(fmaf(nv[k].w, os.y, os.x) - xv[k].w, 0.f);
    *(float4*)(op + k * 256) = o;
  }
}

extern "C" void kernel_launch(void* const* d_in, const int* in_sizes, int n_in,
                              void* d_out, int out_size, void* d_ws, size_t ws_size,
                              hipStream_t stream) {
  const float* x      = (const float*)d_in[0];
  const float* avg0   = (const float*)d_in[1];
  const float* noise  = (const float*)d_in[2];
  const float* conv_w = (const float*)d_in[3];
  const float* conv_b = (const float*)d_in[4];
  const float* keys   = (const float*)d_in[5];
  const float* shapes = (const float*)d_in[6];
  float* out = (float*)d_out;

  _Float16* scoresh = (_Float16*)d_ws;                               // 16.78 MB
  // +4KB pad absorbs the 16-deep prefetch overrun of the last chunk.
  short* frags = (short*)((char*)d_ws + ((size_t)T * BATCH * NP * 2 + 4096)); // 5.6 KB

  prep_kernel<<<1, 64, 0, stream>>>(conv_w, conv_b, keys, frags);
  scores_kernel<<<BATCH * (T / TT), 256, 0, stream>>>(x, frags, scoresh);
  scanout_kernel<<<32 * NCHUNK, 256, 0, stream>>>(scoresh, avg0, shapes, x, noise, out);
}

// Round 16
// 66.956 us; speedup vs baseline: 1.1065x; 1.1065x over previous
//
#include <hip/hip_runtime.h>

static constexpr int BATCH = 128;
static constexpr int LEN   = 131072;
static constexpr int T     = 4096;   // LEN / 32
static constexpr int DIM   = 32;
static constexpr int NP    = 16;

static constexpr int NCHUNK = 64;         // speculative chunks over T
static constexpr int SPC    = T / NCHUNK; // 64 steps per chunk
static constexpr int WARM   = 128;        // warm-up steps (0.9375^128 ~ 2.6e-4)

static constexpr int TT = 128;            // windows per scores-block

#define L2E   1.44269504088896340736f
#define L2E16 (1.44269504088896340736f / 16.0f)

typedef __attribute__((ext_vector_type(8))) short  short8;   // 8 bf16
typedef __attribute__((ext_vector_type(4))) float  f32x4;

__device__ __forceinline__ float fexp2(float x) {
#if __has_builtin(__builtin_amdgcn_exp2f)
  return __builtin_amdgcn_exp2f(x);
#else
  return exp2f(x);
#endif
}

__device__ __forceinline__ float frcp(float x) {
#if __has_builtin(__builtin_amdgcn_rcpf)
  return __builtin_amdgcn_rcpf(x);
#else
  return 1.0f / x;
#endif
}

template <int CTRL>
__device__ __forceinline__ float dppf(float v) {
  return __int_as_float(
      __builtin_amdgcn_update_dpp(0, __float_as_int(v), CTRL, 0xf, 0xf, true));
}

// Sum across each 16-lane group: butterfly over xor {1,2,7,15} via DPP.
__device__ __forceinline__ float sum16(float v) {
  v += dppf<0xB1>(v);
  v += dppf<0x4E>(v);
  v += dppf<0x141>(v);
  v += dppf<0x140>(v);
  return v;
}

// f32 -> bf16 round-to-nearest-even.
__device__ __forceinline__ short bf16c(float f) {
  unsigned u = __float_as_uint(f);
  unsigned r = u + 0x7fffu + ((u >> 16) & 1u);
  return (short)(r >> 16);
}

// One-shot prep: build bf16 MFMA fragments for conv_w / keys / bias in the
// exact per-lane layout scores_kernel consumes.
// Layout (shorts): [fs=fn*2+fk][lane][8] (4x1KB), kfrag [lane][8] (1KB),
// bias float2[lane] (512B). Total 5.6KB -> L1/L2-resident.
__global__ void __launch_bounds__(64) prep_kernel(
    const float* __restrict__ conv_w, const float* __restrict__ conv_b,
    const float* __restrict__ keys, short* __restrict__ frags) {
  int l = threadIdx.x;
  int ln15 = l & 15, kg = l >> 4;
#pragma unroll
  for (int fn = 0; fn < 2; ++fn)
#pragma unroll
    for (int fk = 0; fk < 2; ++fk) {
      const float* wp = conv_w + (fn * 16 + ln15) * 64 + fk * 32 + kg * 8;
      short* dst = frags + ((fn * 2 + fk) * 64 + l) * 8;
#pragma unroll
      for (int j = 0; j < 8; ++j) dst[j] = bf16c(wp[j]);
    }
  short* kd = frags + (256 + l) * 8;
#pragma unroll
  for (int j = 0; j < 8; ++j) kd[j] = bf16c(keys[(kg * 8 + j) * NP + ln15]);
  float* bp = (float*)(frags + 2560);
  bp[2 * l]     = conv_b[ln15];
  bp[2 * l + 1] = conv_b[16 + ln15];
}

// Stage 1 (MFMA, barrier-free): block = 256 thr (4 waves), one b, TT=128
// windows; each WAVE owns 32 windows and stages its OWN 2.1KB x-slice into a
// private LDS region -> no __syncthreads at all (same-wave DS ops are
// in-order). conv as GEMM via 16x16x32 bf16 MFMA (K=64 in 2 steps, N=32 in
// 2 tiles), relu+bias in D-layout, transpose through padded LDS (row stride
// 80B: conflict-free), MFMA vs keys. Fragment layouts (m89-verified):
// A row=l&15,k=(l>>4)*8+j; B col=l&15, same k; C/D col=l&15, row=(l>>4)*4+reg.
__global__ void __launch_bounds__(256) scores_kernel(
    const float* __restrict__ x, const short* __restrict__ frags,
    _Float16* __restrict__ scoresh) {
  // per wave: xw[1088] (windows) + rl[16 rows x 40 shorts padded] = 1728 shorts
  __shared__ short lds[4][1728];

  int tid = threadIdx.x;
  int lane = tid & 63;
  int mt   = tid >> 6;     // wave id
  int blk = blockIdx.x;
  int b  = blk >> 5;
  int bt = blk & 31;
  int t0 = bt * TT;
  int T0w = t0 + mt * 32;              // this wave's first window
  const float* xb = x + (size_t)b * LEN;
  short* xw = lds[mt];                 // xw[i] = bf16(x[32*T0w - 63 + i]), i<1056
  short* rl = lds[mt] + 1088;          // relu(conv) [t][d], row stride 40

  // ---- per-wave staging: lane covers xw[16*lane-1 .. 16*lane+15].
  int gbase = 32 * T0w - 64 + 16 * lane;
  float f[17];
#pragma unroll
  for (int s = 0; s < 4; ++s) {
    int gi = gbase + 4 * s;
    float4 v = make_float4(0.f, 0.f, 0.f, 0.f);
    if (gi >= 0) v = *(const float4*)(xb + gi);   // 16B-aligned
    f[4 * s]     = v.x; f[4 * s + 1] = v.y;
    f[4 * s + 2] = v.z; f[4 * s + 3] = v.w;
  }
  f[16] = (gbase + 16 >= 0) ? xb[gbase + 16] : 0.f;

  short8 w0, w1;
#pragma unroll
  for (int j = 0; j < 8; ++j) { w0[j] = bf16c(f[j + 1]); w1[j] = bf16c(f[j + 9]); }
  *(short8*)(&xw[16 * lane])     = w0;
  *(short8*)(&xw[16 * lane + 8]) = w1;
  if (lane > 0) xw[16 * lane - 1] = bf16c(f[0]);
  if (lane < 32)                        // tail: xw[1024..1055] (global +961..+992)
    xw[1024 + lane] = bf16c(xb[32 * T0w + 961 + lane]);

  int ln15 = lane & 15;
  int kg   = lane >> 4;    // 0..3

  // Prebuilt fragments: 5x16B + 8B, coalesced, L2-hot.
  const short8* wf = (const short8*)frags;
  short8 bw00 = wf[0 * 64 + lane];
  short8 bw01 = wf[1 * 64 + lane];
  short8 bw10 = wf[2 * 64 + lane];
  short8 bw11 = wf[3 * 64 + lane];
  short8 bk   = wf[4 * 64 + lane];
  const float2* bp = (const float2*)(frags + 2560);
  float2 bias = bp[lane];

  _Float16* dstb = scoresh + (b & 3) * 16 + ln15;

#pragma unroll
  for (int st = 0; st < 2; ++st) {
    int tl = st * 16 + ln15;                     // window row within wave
    const short* ap = &xw[32 * tl];              // 16B-aligned (64B row stride)
    short8 a0 = *(const short8*)(ap + kg * 8);
    short8 a1 = *(const short8*)(ap + 32 + kg * 8);

    f32x4 acc0 = {0.f, 0.f, 0.f, 0.f};
    f32x4 acc1 = {0.f, 0.f, 0.f, 0.f};
    acc0 = __builtin_amdgcn_mfma_f32_16x16x32_bf16(a0, bw00, acc0, 0, 0, 0);
    acc0 = __builtin_amdgcn_mfma_f32_16x16x32_bf16(a1, bw01, acc0, 0, 0, 0);
    acc1 = __builtin_amdgcn_mfma_f32_16x16x32_bf16(a0, bw10, acc1, 0, 0, 0);
    acc1 = __builtin_amdgcn_mfma_f32_16x16x32_bf16(a1, bw11, acc1, 0, 0, 0);

    // relu(conv+bias) -> bf16 -> padded LDS [t][d] (transpose).
    // Row stride 40 shorts = 80B: kg*320B % 128B = {0,64} -> 2-way (free).
#pragma unroll
    for (int r = 0; r < 4; ++r) {
      int trow = kg * 4 + r;                     // D row = (l>>4)*4 + r
      rl[trow * 40 + ln15]      = bf16c(fmaxf(acc0[r] + bias.x, 0.f));
      rl[trow * 40 + 16 + ln15] = bf16c(fmaxf(acc1[r] + bias.y, 0.f));
    }
    // Same-wave DS ops are in-order: no barrier needed (reads see writes,
    // next st's writes can't pass this read - WAR safe).
    short8 a2 = *(const short8*)(&rl[ln15 * 40 + kg * 8]);  // 80B rows: aligned
    f32x4 acc2 = {0.f, 0.f, 0.f, 0.f};
    acc2 = __builtin_amdgcn_mfma_f32_16x16x32_bf16(a2, bk, acc2, 0, 0, 0);

    // D2: p = ln15, t = T0w + st*16 + kg*4 + r. clip*log2e -> f16.
#pragma unroll
    for (int r = 0; r < 4; ++r) {
      float s = fminf(fmaxf(acc2[r], 0.f), 6.f) * L2E;
      int t = T0w + st * 16 + kg * 4 + r;
      dstb[((size_t)(b >> 2) * T + t) * 64] = (_Float16)s;
    }
  }
}

// Stage 2+3 FUSED v5: 256-thread blocks, __launch_bounds__(256,8) caps
// VGPR<=64 -> 8 waves/SIMD = 32 waves/CU streaming (the standalone
// out_kernel's 5.1TB/s regime). Streaming waves prefetch ONLY the HBM-cold
// noise stream (8 x float4 = 32 VGPR) and PIN it live before the barrier
// with a data dependency (dummy = sum of .x comps -> asm) -- R15 showed
// branch placement alone gets sunk (VGPR=40); a dependency cannot be.
// x (L3-resident) is loaded inline post-barrier where 8 waves/SIMD TLP
// absorbs its ~300cyc latency. Wave 0 runs the scan, loads its nv after.
__global__ void __launch_bounds__(256, 8) scanout_kernel(
    const _Float16* __restrict__ scoresh, const float* __restrict__ avg0,
    const float* __restrict__ shapes, const float* __restrict__ x,
    const float* __restrict__ noise, float* __restrict__ out) {
  __shared__ float2 oslds[4][64];    // [local batch][t within chunk]

  int tid  = threadIdx.x;
  int lane = tid & 63;
  int wid  = tid >> 6;       // wave id = local batch for the out-phase
  int g = blockIdx.x & 31;   // batch-group (4 batches)
  int c = blockIdx.x >> 5;   // chunk

  size_t base = (size_t)(g * 4) * LEN + (size_t)c * 2048;
  const float* xp = x     + base + (size_t)wid * LEN + lane * 4;
  const float* np = noise + base + (size_t)wid * LEN + lane * 4;

  float4 nv[8];
  if (wid != 0) {
    // Prefetch noise; 8 loads in flight; pinned live below.
#pragma unroll
    for (int k = 0; k < 8; ++k) nv[k] = *(const float4*)(np + k * 256);
    float dummy = nv[0].x + nv[1].x + nv[2].x + nv[3].x +
                  nv[4].x + nv[5].x + nv[6].x + nv[7].x;
    asm volatile("" :: "v"(dummy));   // forces loads complete pre-barrier
  } else {
    // ---- wave 0: speculative scan (R12 structure) ----
    int gid = g * 64 + lane;   // = b*16 + p
    int p = lane & 15;
    int bl = lane >> 4;        // local batch 0..3
    float A = avg0[gid] * L2E;
    float sh0 = shapes[2 * p];
    float sh1 = shapes[2 * p + 1];
    int w = min(WARM, c * SPC);      // c=0 exact; w in {0,64,128} (%16==0)
    int tbeg = c * SPC - w;
    const _Float16* sp = scoresh + ((size_t)g * T + tbeg) * 64 + lane;

    float q0 = (float)sp[0 * 64],  q1 = (float)sp[1 * 64];
    float q2 = (float)sp[2 * 64],  q3 = (float)sp[3 * 64];
    float q4 = (float)sp[4 * 64],  q5 = (float)sp[5 * 64];
    float q6 = (float)sp[6 * 64],  q7 = (float)sp[7 * 64];
    float q8 = (float)sp[8 * 64],  q9 = (float)sp[9 * 64];
    float qa = (float)sp[10 * 64], qb = (float)sp[11 * 64];
    float qc = (float)sp[12 * 64], qd = (float)sp[13 * 64];
    float qe = (float)sp[14 * 64], qf = (float)sp[15 * 64];
    sp += 16 * 64;

#define WSTEP(Q)                                   \
  do {                                             \
    float e = fexp2(Q - A);                        \
    float r = sum16(e);                            \
    A = fmaf(e * L2E, frcp(r), A - L2E16);         \
    Q = (float)sp[0];                              \
    sp += 64;                                      \
  } while (0)

    for (int i = 0; i < w; i += 16) {
      WSTEP(q0); WSTEP(q1); WSTEP(q2); WSTEP(q3);
      WSTEP(q4); WSTEP(q5); WSTEP(q6); WSTEP(q7);
      WSTEP(q8); WSTEP(q9); WSTEP(qa); WSTEP(qb);
      WSTEP(qc); WSTEP(qd); WSTEP(qe); WSTEP(qf);
    }

#define CSTEP(Q, idx)                              \
  do {                                             \
    float e = fexp2(Q - A);                        \
    float r  = sum16(e);                           \
    float u0 = sum16(e * sh0);                     \
    float u1 = sum16(e * sh1);                     \
    float rc = frcp(r);                            \
    A = fmaf(e * L2E, rc, A - L2E16);              \
    if (p == 0) oslds[bl][idx] = make_float2(u0 * rc, u1 * rc); \
    Q = (float)sp[0];                              \
    sp += 64;                                      \
  } while (0)

    for (int i = 0; i < SPC; i += 16) {            // overrun covered by ws pad
      CSTEP(q0, i + 0);  CSTEP(q1, i + 1);  CSTEP(q2, i + 2);  CSTEP(q3, i + 3);
      CSTEP(q4, i + 4);  CSTEP(q5, i + 5);  CSTEP(q6, i + 6);  CSTEP(q7, i + 7);
      CSTEP(q8, i + 8);  CSTEP(q9, i + 9);  CSTEP(qa, i + 10); CSTEP(qb, i + 11);
      CSTEP(qc, i + 12); CSTEP(qd, i + 13); CSTEP(qe, i + 14); CSTEP(qf, i + 15);
    }
#undef WSTEP
#undef CSTEP

    // wave 0's own noise loads (latency covered by other waves on the SIMD).
#pragma unroll
    for (int k = 0; k < 8; ++k) nv[k] = *(const float4*)(np + k * 256);
  }

  __syncthreads();   // oslds (wave 0) visible to all waves

  // ---- out phase: wave wid streams batch 4g+wid, elems [2048c, +2048).
  // x loaded inline (L3-hot, ~300cyc) -- 8 waves/SIMD TLP hides it.
  float* op = out + base + (size_t)wid * LEN + lane * 4;
#pragma unroll
  for (int k = 0; k < 8; ++k) {
    float4 xv = *(const float4*)(xp + k * 256);
    float2 os = oslds[wid][k * 8 + (lane >> 3)];   // t = c*64 + k*8 + (lane>>3)
    float4 o;
    o.x = fmaxf(fmaf(nv[k].x, os.y, os.x) - xv.x, 0.f);
    o.y = fmaxf(fmaf(nv[k].y, os.y, os.x) - xv.y, 0.f);
    o.z = fmaxf(fmaf(nv[k].z, os.y, os.x) - xv.z, 0.f);
    o.w = fmaxf(fmaf(nv[k].w, os.y, os.x) - xv.w, 0.f);
    *(float4*)(op + k * 256) = o;
  }
}

extern "C" void kernel_launch(void* const* d_in, const int* in_sizes, int n_in,
                              void* d_out, int out_size, void* d_ws, size_t ws_size,
                              hipStream_t stream) {
  const float* x      = (const float*)d_in[0];
  const float* avg0   = (const float*)d_in[1];
  const float* noise  = (const float*)d_in[2];
  const float* conv_w = (const float*)d_in[3];
  const float* conv_b = (const float*)d_in[4];
  const float* keys   = (const float*)d_in[5];
  const float* shapes = (const float*)d_in[6];
  float* out = (float*)d_out;

  _Float16* scoresh = (_Float16*)d_ws;                               // 16.78 MB
  // +4KB pad absorbs the 16-deep prefetch overrun of the last chunk.
  short* frags = (short*)((char*)d_ws + ((size_t)T * BATCH * NP * 2 + 4096)); // 5.6 KB

  prep_kernel<<<1, 64, 0, stream>>>(conv_w, conv_b, keys, frags);
  scores_kernel<<<BATCH * (T / TT), 256, 0, stream>>>(x, frags, scoresh);
  scanout_kernel<<<32 * NCHUNK, 256, 0, stream>>>(scoresh, avg0, shapes, x, noise, out);
}